// Round 9
// baseline (260.629 us; speedup 1.0000x reference)
//
#include <hip/hip_runtime.h>
#include <hip/hip_cooperative_groups.h>
#include <math.h>

namespace cg = cooperative_groups;

#define B_ 8
#define L_ 1024
#define K_ 1024
#define D_ 128
#define S_ 16
#define DS_ (D_ * S_)
#define NIT_ 16          // full contraction, BK=64

typedef short bf16x8 __attribute__((ext_vector_type(8)));
typedef float f32x4 __attribute__((ext_vector_type(4)));
typedef __attribute__((address_space(1))) const unsigned int gu32;
typedef __attribute__((address_space(3))) unsigned int lu32;

__device__ inline unsigned short f2bf(float f) {
    unsigned int u = __float_as_uint(f);
    u = (u + 0x7fffu + ((u >> 16) & 1u)) >> 16;   // RNE
    return (unsigned short)u;
}
__device__ inline float bf2f(unsigned short h) {
    return __uint_as_float(((unsigned int)h) << 16);
}

// B operands (u', G) stored PRE-SWIZZLED in glds consumption order:
// idx = ((((b*32 + ct)*4 + q)*128 + n)*8 + i), c = ct*32 + q*8 + i.
__device__ inline size_t bswz(int b, int c, int n) {
    return ((((size_t)b * 32 + (c >> 5)) * 4 + ((c >> 3) & 3)) * 128 + n) * 8;
}

// ---------------------------------------------------------------------------
// k_w (frozen R18): one-time W_in bf16 hi/lo fragment pre-pack.
// ---------------------------------------------------------------------------
__global__ __launch_bounds__(256) void k_w(
    const float* __restrict__ W_in,
    unsigned short* __restrict__ wiH, unsigned short* __restrict__ wiL) {
    int g = blockIdx.x * 256 + threadIdx.x;  // [0,4096)
    int lane = g & 63, rest = g >> 6;        // rest in [0,64)
    int ct = rest & 3, wv = (rest >> 2) & 3, c = rest >> 4;
    int rbase = c * 32 + (lane >> 4) * 8;
    int col = wv * 64 + ct * 16 + (lane & 15);
    bf16x8 hv, lv;
    #pragma unroll
    for (int i = 0; i < 8; ++i) {
        float wvl = W_in[(rbase + i) * 256 + col];
        unsigned short h = f2bf(wvl);
        hv[i] = (short)h;
        lv[i] = (short)f2bf(wvl - bf2f(h));
    }
    *(bf16x8*)&wiH[(size_t)g * 8] = hv;
    *(bf16x8*)&wiL[(size_t)g * 8] = lv;
}

// ---------------------------------------------------------------------------
// k_pre (frozen R18): params (blocks 0-7) + W_out frag pre-pack (blocks 8-11)
// + rownorm + BN + MFMA in-proj (pre-packed W_in frags) + swizzled u.
// ---------------------------------------------------------------------------
__global__ __launch_bounds__(256) void k_pre(
    const float* __restrict__ E, const float* __restrict__ x,
    const float* __restrict__ g, const float* __restrict__ beta,
    const float* __restrict__ mean, const float* __restrict__ var,
    const unsigned short* __restrict__ wiH, const unsigned short* __restrict__ wiL,
    const float* __restrict__ b_in,
    const float* __restrict__ log_Delta, const float* __restrict__ Bp,
    const float* __restrict__ Cp, const float* __restrict__ log_A_real,
    const float* __restrict__ A_imag, const float* __restrict__ W_out,
    float* __restrict__ rn_out, float* __restrict__ par,
    unsigned short* __restrict__ woH, unsigned short* __restrict__ woL,
    unsigned short* __restrict__ uswH, unsigned short* __restrict__ uswL) {
    __shared__ unsigned short xbh[4][16][32], xbl[4][16][32];  // [kchunk][row][k&31]
    __shared__ float szs[16][132];   // silu(z) tile
    __shared__ float us[16][132];    // u tile (rn * x1 * silu(z))
    __shared__ float rsum[16];
    __shared__ float rnS[16];
    int bx = blockIdx.x;
    int row0 = bx * 16;
    int t = threadIdx.x;
    // --- params (double precision), spread over blocks 0-7 ---
    if (bx < 8) {
        int i = bx * 256 + t;                // i = d*S + s
        int d = i >> 4, s = i & 15;
        double delta = exp((double)log_Delta[d]);
        double Are = -exp((double)log_A_real[i]);
        double Aim = (double)A_imag[i];
        double mag = exp(-1e-3 + delta * Are);
        double ang = delta * Aim;
        int o = s * D_ + d;
        par[o]           = (float)(mag * cos(ang));
        par[DS_ + o]     = (float)(mag * sin(ang));
        par[2 * DS_ + o] = (float)(delta * (double)Bp[i] * (double)Cp[i]);
    }
    // --- W_out bf16 hi/lo frag pre-pack (blocks 8-11; kc = bx-8) ---
    if (bx >= 8 && bx < 12) {
        int kc = bx - 8;
        #pragma unroll
        for (int j = 0; j < 16; ++j) {
            int s = t * 16 + j;              // [0,4096)
            int ws = s >> 10, nt = (s >> 9) & 1, ln = (s >> 3) & 63, ii = s & 7;
            int row = kc * 32 + (ln >> 4) * 8 + ii;
            int col = ws * 32 + nt * 16 + (ln & 15);
            float wv = W_out[row * 128 + col];
            unsigned short h = f2bf(wv);
            woH[kc * 4096 + s] = h;
            woL[kc * 4096 + s] = f2bf(wv - bf2f(h));
        }
    }
    // --- row norms: 16 threads per row ---
    {
        int r = t >> 4, tt = t & 15;
        const float4* Ep = (const float4*)(E + (size_t)(row0 + r) * K_);
        float s = 0.f;
        #pragma unroll
        for (int i = 0; i < 16; ++i) {
            float4 v = Ep[tt + i * 16];
            s += v.x * v.x + v.y * v.y + v.z * v.z + v.w * v.w;
        }
        s += __shfl_xor(s, 8, 64);
        s += __shfl_xor(s, 4, 64);
        s += __shfl_xor(s, 2, 64);
        s += __shfl_xor(s, 1, 64);
        if (tt == 0) rsum[r] = s;
    }
    // --- stage BN(x) directly as bf16 hi/lo in MFMA-A layout ---
    #pragma unroll
    for (int p = 0; p < 8; ++p) {
        int idx = t + p * 256;
        int dd = idx & 127, r = idx >> 7;
        float sc = g[dd] / sqrtf(var[dd] + 1e-5f);
        float v = (x[(size_t)(row0 + r) * D_ + dd] - mean[dd]) * sc + beta[dd];
        unsigned short h = f2bf(v);
        xbh[dd >> 5][r][dd & 31] = h;
        xbl[dd >> 5][r][dd & 31] = f2bf(v - bf2f(h));
    }
    __syncthreads();
    if (t < 16) {
        float rv = 1.0f / sqrtf(rsum[t]);
        rnS[t] = rv;
        rn_out[row0 + t] = rv;
    }
    __syncthreads();
    // --- MFMA in-proj: wave w owns cols [64w, 64w+64); W_in frags pre-packed ---
    int wave = t >> 6, lane = t & 63;
    int fr = lane & 15, q = lane >> 4;
    const bf16x8* WIH = (const bf16x8*)wiH;
    const bf16x8* WIL = (const bf16x8*)wiL;
    f32x4 acc[4];
    #pragma unroll
    for (int ct = 0; ct < 4; ++ct) acc[ct] = (f32x4){0.f, 0.f, 0.f, 0.f};
    #pragma unroll
    for (int c = 0; c < 4; ++c) {
        bf16x8 ah = *(const bf16x8*)&xbh[c][fr][q * 8];
        bf16x8 al = *(const bf16x8*)&xbl[c][fr][q * 8];
        #pragma unroll
        for (int ct = 0; ct < 4; ++ct) {
            int idx = ((c * 4 + wave) * 4 + ct) * 64 + lane;
            bf16x8 bh = WIH[idx];
            bf16x8 bl = WIL[idx];
            acc[ct] = __builtin_amdgcn_mfma_f32_16x16x32_bf16(ah, bh, acc[ct], 0, 0, 0);
            acc[ct] = __builtin_amdgcn_mfma_f32_16x16x32_bf16(ah, bl, acc[ct], 0, 0, 0);
            acc[ct] = __builtin_amdgcn_mfma_f32_16x16x32_bf16(al, bh, acc[ct], 0, 0, 0);
        }
    }
    // --- z-silu (waves 2,3): C/D layout col=fr-side, row=q*4+r ---
    if (wave >= 2) {
        #pragma unroll
        for (int ct = 0; ct < 4; ++ct) {
            int cz = (wave - 2) * 64 + ct * 16 + fr;   // z col in [0,128)
            float b2v = b_in[128 + cz];
            #pragma unroll
            for (int r = 0; r < 4; ++r) {
                float z = acc[ct][r] + b2v;
                float sig = 1.0f / (1.0f + __expf(-z));
                szs[q * 4 + r][cz] = z * sig;
            }
        }
    }
    __syncthreads();
    // --- u = rn * x1 * silu(z) (waves 0,1) ---
    if (wave < 2) {
        #pragma unroll
        for (int ct = 0; ct < 4; ++ct) {
            int cx = wave * 64 + ct * 16 + fr;
            float b1v = b_in[cx];
            #pragma unroll
            for (int r = 0; r < 4; ++r) {
                int row = q * 4 + r;
                float x1 = acc[ct][r] + b1v;
                us[row][cx] = rnS[row] * x1 * szs[row][cx];
            }
        }
    }
    __syncthreads();
    // --- pack & swizzled write-out (proven tail, unchanged) ---
    int j = t & 127, half = t >> 7;
    bf16x8 hv, lv;
    #pragma unroll
    for (int r = 0; r < 8; ++r) {
        float uv = us[half * 8 + r][j];
        unsigned short h = f2bf(uv);
        hv[r] = (short)h;
        lv[r] = (short)f2bf(uv - bf2f(h));
    }
    int b = row0 >> 10;
    int l0 = (row0 & 1023) + half * 8;
    size_t off = bswz(b, l0, j);
    *(bf16x8*)&uswH[off] = hv;
    *(bf16x8*)&uswL[off] = lv;
}

// ---------------------------------------------------------------------------
// R15 GEMM structure macros (frozen).
// ---------------------------------------------------------------------------
#define STAGE_B(itS, nb)                                                        \
    _Pragma("unroll")                                                           \
    for (int j2 = 0; j2 < 4; ++j2) {                                            \
        int s = wave * 4 + j2;           /* [0,32) over 8 waves */              \
        int cts = s >> 4, s2 = s & 15;                                          \
        int qq = s2 & 3, nh = (s2 >> 2) & 1, hl = s2 >> 3;                      \
        size_t src0 = (size_t)((itS) * 2 + cts) * 4096;                         \
        const unsigned short* src =                                             \
            (hl ? BbL : BbH) + src0 + ((size_t)qq * 128 + nh * 64 + lane) * 8;  \
        unsigned short* dst =                                                   \
            (hl ? &sBl[nb][cts][0] : &sBh[nb][cts][0]) + qq * 1032 + nh * 512;  \
        __builtin_amdgcn_global_load_lds((gu32*)src, (lu32*)dst, 16, 0, 0);     \
    }

#define G1_WRITE_A(nb, v0, v1, v2, v3)                                           \
    {                                                                            \
        unsigned short h0 = f2bf(v0), h1 = f2bf(v1);                             \
        unsigned short l0 = f2bf((v0) - bf2f(h0)), l1 = f2bf((v1) - bf2f(h1));   \
        *(unsigned int*)&sAh[nb][0][aoff] = (unsigned)h0 | ((unsigned)h1 << 16); \
        *(unsigned int*)&sAl[nb][0][aoff] = (unsigned)l0 | ((unsigned)l1 << 16); \
        unsigned short h2 = f2bf(v2), h3 = f2bf(v3);                             \
        unsigned short l2 = f2bf((v2) - bf2f(h2)), l3 = f2bf((v3) - bf2f(h3));   \
        *(unsigned int*)&sAh[nb][1][aoff] = (unsigned)h2 | ((unsigned)h3 << 16); \
        *(unsigned int*)&sAl[nb][1][aoff] = (unsigned)l2 | ((unsigned)l3 << 16); \
    }

#define MFMA_PHASE(aB, cB)                                                       \
    {                                                                            \
        __builtin_amdgcn_s_setprio(1);                                           \
        bf16x8 ah[2], al[2], bh[2], bl[2];                                       \
        _Pragma("unroll")                                                        \
        for (int mt = 0; mt < 2; ++mt) {                                         \
            int row = mt * 16 + fr;                                              \
            int p = (q + (row >> 3)) & 3;                                        \
            int offA = row * 40 + p * 8;                                         \
            ah[mt] = *(const bf16x8*)&sAh[aB][kh][offA];                         \
            al[mt] = *(const bf16x8*)&sAl[aB][kh][offA];                         \
        }                                                                        \
        _Pragma("unroll")                                                        \
        for (int nt = 0; nt < 2; ++nt) {                                         \
            int offB = q * 1032 + (wn + nt * 16 + fr) * 8;                       \
            bh[nt] = *(const bf16x8*)&sBh[cB][kh][offB];                         \
            bl[nt] = *(const bf16x8*)&sBl[cB][kh][offB];                         \
        }                                                                        \
        _Pragma("unroll")                                                        \
        for (int mt = 0; mt < 2; ++mt)                                           \
            _Pragma("unroll")                                                    \
            for (int nt = 0; nt < 2; ++nt) {                                     \
                acc[mt][nt] = __builtin_amdgcn_mfma_f32_16x16x32_bf16(ah[mt], bh[nt], acc[mt][nt], 0, 0, 0); \
                acc[mt][nt] = __builtin_amdgcn_mfma_f32_16x16x32_bf16(ah[mt], bl[nt], acc[mt][nt], 0, 0, 0); \
                acc[mt][nt] = __builtin_amdgcn_mfma_f32_16x16x32_bf16(al[mt], bh[nt], acc[mt][nt], 0, 0, 0); \
            }                                                                    \
        __builtin_amdgcn_s_setprio(0);                                           \
    }

#define G2_WRITE_A(nb, va)                                                       \
    {                                                                            \
        unsigned short h0 = f2bf((va).x), h1 = f2bf((va).y);                     \
        unsigned short h2 = f2bf((va).z), h3 = f2bf((va).w);                     \
        unsigned short l0 = f2bf((va).x - bf2f(h0)), l1 = f2bf((va).y - bf2f(h1));\
        unsigned short l2 = f2bf((va).z - bf2f(h2)), l3 = f2bf((va).w - bf2f(h3));\
        *(uint2*)&sAh[nb][chunk][aoff] =                                         \
            (uint2){(unsigned)h0 | ((unsigned)h1 << 16),                         \
                    (unsigned)h2 | ((unsigned)h3 << 16)};                        \
        *(uint2*)&sAl[nb][chunk][aoff] =                                         \
            (uint2){(unsigned)l0 | ((unsigned)l1 << 16),                         \
                    (unsigned)l2 | ((unsigned)l3 << 16)};                        \
    }

// ---------------------------------------------------------------------------
// k_gg (R19): cooperative merge of k_g1 (R18) + k_g2 (R17).
// Grid = 256 blocks x 512 thr = exactly 1 block/CU at 119.7 KB LDS -> all
// blocks co-resident; grid.sync() + __threadfence() at the Gsw boundary
// replaces the k_g1->k_g2 kernel boundary. Phase-2's A-prologue load and
// rnS fill are issued BEFORE the sync (depend only on E/rn), hiding their
// latency under the grid barrier. Both phase bodies are frozen.
// ---------------------------------------------------------------------------
__global__ __launch_bounds__(512, 2) void k_gg(
    const float* __restrict__ E,
    const unsigned short* __restrict__ uswH, const unsigned short* __restrict__ uswL,
    const float* __restrict__ EigVals, const float* __restrict__ par,
    unsigned short* __restrict__ GswH, unsigned short* __restrict__ GswL,
    const float* __restrict__ rn,
    const unsigned short* __restrict__ woH, const unsigned short* __restrict__ woL,
    const float* __restrict__ b_out, float* __restrict__ y) {
    __shared__ alignas(16) unsigned short sAh[2][2][1280], sAl[2][2][1280];
    __shared__ alignas(16) unsigned short sBh[3][2][4128], sBl[3][2][4128];
    __shared__ float evS[32];
    __shared__ float rnS[32];
    int bx = blockIdx.x;
    int b = bx & 7;
    int m0 = (bx >> 3) * 32;                 // k-tile / l-tile base
    const float* Ab = E + (size_t)b * (1024 * 1024);
    int t = threadIdx.x;
    int wave = t >> 6, lane = t & 63;
    int fr = lane & 15, q = lane >> 4;
    int kh = wave & 1;                        // k-split half
    int wn = (wave >> 1) * 32;                // n-slot

    // ======================= PHASE 1: k_g1 =======================
    {
        const unsigned short* BbH = uswH + (size_t)b * 131072;
        const unsigned short* BbL = uswL + (size_t)b * 131072;
        // A staging: thread t handles m=am, c-pairs {2jj,2jj+1} (chunk0) and +32
        int am = t & 31, jj = t >> 5;            // jj in [0,16)
        int ag = jj >> 2;
        int arot = (ag + (am >> 3)) & 3;
        int aoff = am * 40 + arot * 8 + ((2 * jj) & 7);
        if (t < 32) evS[t] = 1.0f - EigVals[b * 1024 + m0 + t];
        f32x4 acc[2][2];
        #pragma unroll
        for (int mt = 0; mt < 2; ++mt)
            #pragma unroll
            for (int nt = 0; nt < 2; ++nt)
                acc[mt][nt] = (f32x4){0.f, 0.f, 0.f, 0.f};

        // ---- prologue: B tiles 0,1 -> ring bufs 0,1; A tile 0 -> Abuf0 ----
        {
            STAGE_B(0, 0);
            STAGE_B(1, 1);
            float v0 = Ab[(size_t)(2 * jj) * 1024 + m0 + am];
            float v1 = Ab[(size_t)(2 * jj + 1) * 1024 + m0 + am];
            float v2 = Ab[(size_t)(32 + 2 * jj) * 1024 + m0 + am];
            float v3 = Ab[(size_t)(32 + 2 * jj + 1) * 1024 + m0 + am];
            G1_WRITE_A(0, v0, v1, v2, v3);
            asm volatile("s_waitcnt vmcnt(0) lgkmcnt(0)" ::: "memory");
            __builtin_amdgcn_s_barrier();
            asm volatile("" ::: "memory");
        }

        for (int it = 0; it < NIT_; ++it) {
            int cB = it % 3;
            int fB = (it + 2) % 3;
            int aB = it & 1, naB = aB ^ 1;
            float v0 = 0.f, v1 = 0.f, v2 = 0.f, v3 = 0.f;
            if (it + 1 < NIT_) {
                int cb = (it + 1) * 64;
                v0 = Ab[(size_t)(cb + 2 * jj) * 1024 + m0 + am];
                v1 = Ab[(size_t)(cb + 2 * jj + 1) * 1024 + m0 + am];
                v2 = Ab[(size_t)(cb + 32 + 2 * jj) * 1024 + m0 + am];
                v3 = Ab[(size_t)(cb + 32 + 2 * jj + 1) * 1024 + m0 + am];
            }
            if (it + 2 < NIT_) STAGE_B(it + 2, fB);
            MFMA_PHASE(aB, cB)
            if (it + 1 < NIT_) G1_WRITE_A(naB, v0, v1, v2, v3);
            asm volatile("s_waitcnt lgkmcnt(0)" ::: "memory");
            __builtin_amdgcn_s_barrier();
            asm volatile("" ::: "memory");
        }

        // ---- epilogue phase 1: kh-merge partial accs into Gs (alias sBh) ----
        float (*Gs)[132] = (float (*)[132])(&sBh[0][0][0]);
        if (kh == 0) {
            #pragma unroll
            for (int mt = 0; mt < 2; ++mt)
                #pragma unroll
                for (int nt = 0; nt < 2; ++nt) {
                    int col = wn + nt * 16 + fr;
                    #pragma unroll
                    for (int r = 0; r < 4; ++r)
                        Gs[mt * 16 + q * 4 + r][col] = acc[mt][nt][r];
                }
        }
        __syncthreads();
        if (kh == 1) {
            #pragma unroll
            for (int mt = 0; mt < 2; ++mt)
                #pragma unroll
                for (int nt = 0; nt < 2; ++nt) {
                    int col = wn + nt * 16 + fr;
                    #pragma unroll
                    for (int r = 0; r < 4; ++r)
                        Gs[mt * 16 + q * 4 + r][col] += acc[mt][nt][r];
                }
        }
        __syncthreads();
        // ---- gepi: Gs *= w(ev,col); pairwise-denominator rational sum ----
        {
            int col = t & 127, rowg = t >> 7;    // 4 groups x 8 rows
            float arr[S_], aii[S_], ccc[S_];
            #pragma unroll
            for (int ss = 0; ss < S_; ++ss) {
                arr[ss] = par[ss * D_ + col];
                aii[ss] = par[DS_ + ss * D_ + col];
                ccc[ss] = par[2 * DS_ + ss * D_ + col];
            }
            #pragma unroll
            for (int i = 0; i < 8; ++i) {
                int row = rowg * 8 + i;
                float ev = evS[row];
                float w = 0.f;
                #pragma unroll
                for (int sp = 0; sp < 8; ++sp) {
                    float n0, n1, d0, d1;
                    {
                        int ss = sp * 2;
                        float a = ev * arr[ss], bi = ev * aii[ss];
                        float oma = 1.0f - a;            // exact (Sterbenz)
                        d0 = fmaf(oma, oma, bi * bi);    // den, no cancellation
                        n0 = ccc[ss] * (oma - d0);       // num == oma - den
                    }
                    {
                        int ss = sp * 2 + 1;
                        float a = ev * arr[ss], bi = ev * aii[ss];
                        float oma = 1.0f - a;
                        d1 = fmaf(oma, oma, bi * bi);
                        n1 = ccc[ss] * (oma - d1);
                    }
                    float num = fmaf(n0, d1, n1 * d0);
                    float dpr = d0 * d1;                 // >= ~1e-12
                    float rr = __builtin_amdgcn_rcpf(dpr);
                    rr = rr * (2.0f - dpr * rr);
                    w = fmaf(num, rr, w);
                }
                Gs[row][col] *= w;
            }
        }
        __syncthreads();
        // ---- swizzled bf16 hi/lo write-out (32 rows = one full ct) ----
        {
            int d = t & 127, kg = t >> 7;        // kg in [0,4): rows kg*8..+8
            bf16x8 hv, lv;
            #pragma unroll
            for (int i = 0; i < 8; ++i) {
                float v = Gs[kg * 8 + i][d];
                unsigned short h = f2bf(v);
                hv[i] = (short)h;
                lv[i] = (short)f2bf(v - bf2f(h));
            }
            int ct = m0 >> 5;
            size_t off = (((size_t)(b * 32 + ct) * 4 + kg) * 128 + d) * 8;
            *(bf16x8*)&GswH[off] = hv;
            *(bf16x8*)&GswL[off] = lv;
        }
    }

    // ---- pre-sync phase-2 prefetch (depends only on E / rn) ----
    int am2 = t >> 4, c42 = (t & 15) * 4;
    float4 va0 = *(const float4*)&Ab[(size_t)(m0 + am2) * 1024 + c42];
    if (t < 32) rnS[t] = rn[b * 1024 + m0 + t];

    // ======================= GRID SYNC =======================
    __threadfence();                          // device-scope release of Gsw
    cg::this_grid().sync();

    // ======================= PHASE 2: k_g2 =======================
    {
        const unsigned short* BbH = GswH + (size_t)b * 131072;
        const unsigned short* BbL = GswL + (size_t)b * 131072;
        int am = am2, c4 = c42;
        int chunk = c4 >> 5, cw = c4 & 31;
        int ag = cw >> 3;
        int arot = (ag + (am >> 3)) & 3;
        int aoff = am * 40 + arot * 8 + (cw & 7);
        f32x4 acc[2][2];
        #pragma unroll
        for (int mt = 0; mt < 2; ++mt)
            #pragma unroll
            for (int nt = 0; nt < 2; ++nt)
                acc[mt][nt] = (f32x4){0.f, 0.f, 0.f, 0.f};

        // ---- prologue (A tile 0 already in va0) ----
        {
            STAGE_B(0, 0);
            STAGE_B(1, 1);
            G2_WRITE_A(0, va0);
            asm volatile("s_waitcnt vmcnt(0) lgkmcnt(0)" ::: "memory");
            __builtin_amdgcn_s_barrier();
            asm volatile("" ::: "memory");
        }

        for (int it = 0; it < NIT_; ++it) {
            int cB = it % 3;
            int fB = (it + 2) % 3;
            int aB = it & 1, naB = aB ^ 1;
            float4 va = (float4){0.f, 0.f, 0.f, 0.f};
            if (it + 1 < NIT_)
                va = *(const float4*)&Ab[(size_t)(m0 + am) * 1024 + (it + 1) * 64 + c4];
            if (it + 2 < NIT_) STAGE_B(it + 2, fB);
            MFMA_PHASE(aB, cB)
            if (it + 1 < NIT_) G2_WRITE_A(naB, va);
            asm volatile("s_waitcnt lgkmcnt(0)" ::: "memory");
            __builtin_amdgcn_s_barrier();
            asm volatile("" ::: "memory");
        }

        // ---- epilogue: kh-merge raw accs into Ysf (alias sBh) ----
        float (*Ysf)[132] = (float (*)[132])(&sBh[0][0][0]);
        if (kh == 0) {
            #pragma unroll
            for (int mt = 0; mt < 2; ++mt)
                #pragma unroll
                for (int nt = 0; nt < 2; ++nt) {
                    int col = wn + nt * 16 + fr;
                    #pragma unroll
                    for (int r = 0; r < 4; ++r)
                        Ysf[mt * 16 + q * 4 + r][col] = acc[mt][nt][r];
                }
        }
        __syncthreads();
        if (kh == 1) {
            #pragma unroll
            for (int mt = 0; mt < 2; ++mt)
                #pragma unroll
                for (int nt = 0; nt < 2; ++nt) {
                    int col = wn + nt * 16 + fr;
                    #pragma unroll
                    for (int r = 0; r < 4; ++r)
                        Ysf[mt * 16 + q * 4 + r][col] += acc[mt][nt][r];
                }
        }
        __syncthreads();
        // ---- rn + silu -> bf16 hi/lo A-tile in dead sBl (40-short rows) ----
        unsigned short (*ysh)[32][40] = (unsigned short (*)[32][40])(&sBl[0][0][0]);
        unsigned short (*ysl)[32][40] = (unsigned short (*)[32][40])(&sBl[0][0][0] + 5120);
        {
            int col = t & 127, rowg = t >> 7;    // 4 groups x 8 rows
            #pragma unroll
            for (int i = 0; i < 8; ++i) {
                int row = rowg * 8 + i;
                float v = Ysf[row][col] * rnS[row];
                float sig = 1.0f / (1.0f + __expf(-v));
                float u = v * sig;
                unsigned short h = f2bf(u);
                ysh[col >> 5][row][col & 31] = h;
                ysl[col >> 5][row][col & 31] = f2bf(u - bf2f(h));
            }
        }
        __syncthreads();
        // ---- MFMA out-proj: wave (mh = wave&1 m-half, ws = wave>>1 n-slot) ----
        {
            int mh = wave & 1, ws = wave >> 1;
            const bf16x8* WH = (const bf16x8*)woH;
            const bf16x8* WL = (const bf16x8*)woL;
            f32x4 a2[2];
            a2[0] = (f32x4){0.f, 0.f, 0.f, 0.f};
            a2[1] = (f32x4){0.f, 0.f, 0.f, 0.f};
            #pragma unroll
            for (int kc = 0; kc < 4; ++kc) {
                bf16x8 ah = *(const bf16x8*)&ysh[kc][mh * 16 + fr][q * 8];
                bf16x8 al = *(const bf16x8*)&ysl[kc][mh * 16 + fr][q * 8];
                #pragma unroll
                for (int nt = 0; nt < 2; ++nt) {
                    bf16x8 bh = WH[((kc * 4 + ws) * 2 + nt) * 64 + lane];
                    bf16x8 bl = WL[((kc * 4 + ws) * 2 + nt) * 64 + lane];
                    a2[nt] = __builtin_amdgcn_mfma_f32_16x16x32_bf16(ah, bh, a2[nt], 0, 0, 0);
                    a2[nt] = __builtin_amdgcn_mfma_f32_16x16x32_bf16(ah, bl, a2[nt], 0, 0, 0);
                    a2[nt] = __builtin_amdgcn_mfma_f32_16x16x32_bf16(al, bh, a2[nt], 0, 0, 0);
                }
            }
            #pragma unroll
            for (int nt = 0; nt < 2; ++nt) {
                int col = ws * 32 + nt * 16 + fr;
                float bo = b_out[col];
                #pragma unroll
                for (int r = 0; r < 4; ++r) {
                    int row = mh * 16 + q * 4 + r;
                    y[((size_t)b * 1024 + m0 + row) * 128 + col] = a2[nt][r] + bo;
                }
            }
        }
    }
}

// ---------------------------------------------------------------------------
extern "C" void kernel_launch(void* const* d_in, const int* in_sizes, int n_in,
                              void* d_out, int out_size, void* d_ws, size_t ws_size,
                              hipStream_t stream) {
    const float* x          = (const float*)d_in[0];
    const float* EigVecs    = (const float*)d_in[2];
    const float* EigVals    = (const float*)d_in[3];
    const float* bn_gamma   = (const float*)d_in[4];
    const float* bn_beta    = (const float*)d_in[5];
    const float* bn_mean    = (const float*)d_in[6];
    const float* bn_var     = (const float*)d_in[7];
    const float* W_in       = (const float*)d_in[8];
    const float* b_in       = (const float*)d_in[9];
    const float* log_Delta  = (const float*)d_in[10];
    const float* Bp         = (const float*)d_in[11];
    const float* Cp         = (const float*)d_in[12];
    const float* log_A_real = (const float*)d_in[13];
    const float* A_imag     = (const float*)d_in[14];
    const float* W_out      = (const float*)d_in[15];
    const float* b_out      = (const float*)d_in[16];

    float* y = (float*)d_out;
    char* w = (char*)d_ws;
    float* rn            = (float*)(w);                       // 32 KB
    float* par           = (float*)(w + 32768);               // 24 KB
    unsigned short* woH  = (unsigned short*)(w + 57344);      // 32 KB
    unsigned short* woL  = (unsigned short*)(w + 90112);      // 32 KB
    unsigned short* wiH  = (unsigned short*)(w + 131072);     // 64 KB
    unsigned short* wiL  = (unsigned short*)(w + 196608);     // 64 KB
    unsigned short* uswH = (unsigned short*)(w + 262144);     // 2 MB each
    unsigned short* uswL = (unsigned short*)(w + 262144 + (1u << 21));
    unsigned short* GswH = (unsigned short*)(w + 262144 + 2 * (1u << 21));
    unsigned short* GswL = (unsigned short*)(w + 262144 + 3 * (1u << 21));

    k_w<<<dim3(16), dim3(256), 0, stream>>>(W_in, wiH, wiL);
    k_pre<<<dim3(B_ * L_ / 16), dim3(256), 0, stream>>>(
        EigVecs, x, bn_gamma, bn_beta, bn_mean, bn_var, wiH, wiL, b_in,
        log_Delta, Bp, Cp, log_A_real, A_imag, W_out, rn, par, woH, woL,
        uswH, uswL);
    {
        const float* E_ = EigVecs;
        const unsigned short* BH_ = uswH;
        const unsigned short* BL_ = uswL;
        const float* EV_ = EigVals;
        const float* par_ = par;
        unsigned short* GH_ = GswH;
        unsigned short* GL_ = GswL;
        const float* rn_ = rn;
        const unsigned short* WH_ = woH;
        const unsigned short* WL_ = woL;
        const float* bo_ = b_out;
        float* y_ = y;
        void* args[] = {(void*)&E_, (void*)&BH_, (void*)&BL_, (void*)&EV_,
                        (void*)&par_, (void*)&GH_, (void*)&GL_, (void*)&rn_,
                        (void*)&WH_, (void*)&WL_, (void*)&bo_, (void*)&y_};
        hipLaunchCooperativeKernel((const void*)k_gg, dim3(256), dim3(512),
                                   args, 0, stream);
    }
}

// Round 10
// 152.130 us; speedup vs baseline: 1.7132x; 1.7132x over previous
//
#include <hip/hip_runtime.h>
#include <math.h>

#define B_ 8
#define L_ 1024
#define K_ 1024
#define D_ 128
#define S_ 16
#define DS_ (D_ * S_)
#define NIT_ 16          // full contraction, BK=64

typedef short bf16x8 __attribute__((ext_vector_type(8)));
typedef float f32x4 __attribute__((ext_vector_type(4)));
typedef __attribute__((address_space(1))) const unsigned int gu32;
typedef __attribute__((address_space(3))) unsigned int lu32;

__device__ inline unsigned short f2bf(float f) {
    unsigned int u = __float_as_uint(f);
    u = (u + 0x7fffu + ((u >> 16) & 1u)) >> 16;   // RNE
    return (unsigned short)u;
}
__device__ inline float bf2f(unsigned short h) {
    return __uint_as_float(((unsigned int)h) << 16);
}

// B operands (u', G) stored PRE-SWIZZLED in glds consumption order:
// idx = ((((b*32 + ct)*4 + q)*128 + n)*8 + i), c = ct*32 + q*8 + i.
__device__ inline size_t bswz(int b, int c, int n) {
    return ((((size_t)b * 32 + (c >> 5)) * 4 + ((c >> 3) & 3)) * 128 + n) * 8;
}

// ---------------------------------------------------------------------------
// k_w (R18): one-time W_in bf16 hi/lo fragment pre-pack.
// Granule g = ((c*4 + wv)*4 + ct)*64 + lane holds, at [g*8 + i]:
//   W_in[(c*32 + (lane>>4)*8 + i)*256 + wv*64 + ct*16 + (lane&15)]
// -- exactly k_pre's in-proj B-frag consumption order. 16 blocks x 256 thr.
// ---------------------------------------------------------------------------
__global__ __launch_bounds__(256) void k_w(
    const float* __restrict__ W_in,
    unsigned short* __restrict__ wiH, unsigned short* __restrict__ wiL) {
    int g = blockIdx.x * 256 + threadIdx.x;  // [0,4096)
    int lane = g & 63, rest = g >> 6;        // rest in [0,64)
    int ct = rest & 3, wv = (rest >> 2) & 3, c = rest >> 4;
    int rbase = c * 32 + (lane >> 4) * 8;
    int col = wv * 64 + ct * 16 + (lane & 15);
    bf16x8 hv, lv;
    #pragma unroll
    for (int i = 0; i < 8; ++i) {
        float wvl = W_in[(rbase + i) * 256 + col];
        unsigned short h = f2bf(wvl);
        hv[i] = (short)h;
        lv[i] = (short)f2bf(wvl - bf2f(h));
    }
    *(bf16x8*)&wiH[(size_t)g * 8] = hv;
    *(bf16x8*)&wiL[(size_t)g * 8] = lv;
}

// ---------------------------------------------------------------------------
// k_pre (R18): params (blocks 0-7) + W_out frag pre-pack (blocks 8-11) +
// rownorm + BN + MFMA in-proj (W_in frags read PRE-PACKED from wiH/wiL) +
// swizzled bf16 hi/lo u. 16 rows/block, 512 blocks, 256 threads (4 waves).
// ---------------------------------------------------------------------------
__global__ __launch_bounds__(256) void k_pre(
    const float* __restrict__ E, const float* __restrict__ x,
    const float* __restrict__ g, const float* __restrict__ beta,
    const float* __restrict__ mean, const float* __restrict__ var,
    const unsigned short* __restrict__ wiH, const unsigned short* __restrict__ wiL,
    const float* __restrict__ b_in,
    const float* __restrict__ log_Delta, const float* __restrict__ Bp,
    const float* __restrict__ Cp, const float* __restrict__ log_A_real,
    const float* __restrict__ A_imag, const float* __restrict__ W_out,
    float* __restrict__ rn_out, float* __restrict__ par,
    unsigned short* __restrict__ woH, unsigned short* __restrict__ woL,
    unsigned short* __restrict__ uswH, unsigned short* __restrict__ uswL) {
    __shared__ unsigned short xbh[4][16][32], xbl[4][16][32];  // [kchunk][row][k&31]
    __shared__ float szs[16][132];   // silu(z) tile
    __shared__ float us[16][132];    // u tile (rn * x1 * silu(z))
    __shared__ float rsum[16];
    __shared__ float rnS[16];
    int bx = blockIdx.x;
    int row0 = bx * 16;
    int t = threadIdx.x;
    // --- params (double precision), spread over blocks 0-7 ---
    if (bx < 8) {
        int i = bx * 256 + t;                // i = d*S + s
        int d = i >> 4, s = i & 15;
        double delta = exp((double)log_Delta[d]);
        double Are = -exp((double)log_A_real[i]);
        double Aim = (double)A_imag[i];
        double mag = exp(-1e-3 + delta * Are);
        double ang = delta * Aim;
        int o = s * D_ + d;
        par[o]           = (float)(mag * cos(ang));
        par[DS_ + o]     = (float)(mag * sin(ang));
        par[2 * DS_ + o] = (float)(delta * (double)Bp[i] * (double)Cp[i]);
    }
    // --- W_out bf16 hi/lo frag pre-pack (blocks 8-11; kc = bx-8) ---
    if (bx >= 8 && bx < 12) {
        int kc = bx - 8;
        #pragma unroll
        for (int j = 0; j < 16; ++j) {
            int s = t * 16 + j;              // [0,4096)
            int ws = s >> 10, nt = (s >> 9) & 1, ln = (s >> 3) & 63, ii = s & 7;
            int row = kc * 32 + (ln >> 4) * 8 + ii;
            int col = ws * 32 + nt * 16 + (ln & 15);
            float wv = W_out[row * 128 + col];
            unsigned short h = f2bf(wv);
            woH[kc * 4096 + s] = h;
            woL[kc * 4096 + s] = f2bf(wv - bf2f(h));
        }
    }
    // --- row norms: 16 threads per row ---
    {
        int r = t >> 4, tt = t & 15;
        const float4* Ep = (const float4*)(E + (size_t)(row0 + r) * K_);
        float s = 0.f;
        #pragma unroll
        for (int i = 0; i < 16; ++i) {
            float4 v = Ep[tt + i * 16];
            s += v.x * v.x + v.y * v.y + v.z * v.z + v.w * v.w;
        }
        s += __shfl_xor(s, 8, 64);
        s += __shfl_xor(s, 4, 64);
        s += __shfl_xor(s, 2, 64);
        s += __shfl_xor(s, 1, 64);
        if (tt == 0) rsum[r] = s;
    }
    // --- stage BN(x) directly as bf16 hi/lo in MFMA-A layout ---
    #pragma unroll
    for (int p = 0; p < 8; ++p) {
        int idx = t + p * 256;
        int dd = idx & 127, r = idx >> 7;
        float sc = g[dd] / sqrtf(var[dd] + 1e-5f);
        float v = (x[(size_t)(row0 + r) * D_ + dd] - mean[dd]) * sc + beta[dd];
        unsigned short h = f2bf(v);
        xbh[dd >> 5][r][dd & 31] = h;
        xbl[dd >> 5][r][dd & 31] = f2bf(v - bf2f(h));
    }
    __syncthreads();
    if (t < 16) {
        float rv = 1.0f / sqrtf(rsum[t]);
        rnS[t] = rv;
        rn_out[row0 + t] = rv;
    }
    __syncthreads();
    // --- MFMA in-proj: wave w owns cols [64w, 64w+64); W_in frags pre-packed ---
    int wave = t >> 6, lane = t & 63;
    int fr = lane & 15, q = lane >> 4;
    const bf16x8* WIH = (const bf16x8*)wiH;
    const bf16x8* WIL = (const bf16x8*)wiL;
    f32x4 acc[4];
    #pragma unroll
    for (int ct = 0; ct < 4; ++ct) acc[ct] = (f32x4){0.f, 0.f, 0.f, 0.f};
    #pragma unroll
    for (int c = 0; c < 4; ++c) {
        bf16x8 ah = *(const bf16x8*)&xbh[c][fr][q * 8];
        bf16x8 al = *(const bf16x8*)&xbl[c][fr][q * 8];
        #pragma unroll
        for (int ct = 0; ct < 4; ++ct) {
            int idx = ((c * 4 + wave) * 4 + ct) * 64 + lane;
            bf16x8 bh = WIH[idx];
            bf16x8 bl = WIL[idx];
            acc[ct] = __builtin_amdgcn_mfma_f32_16x16x32_bf16(ah, bh, acc[ct], 0, 0, 0);
            acc[ct] = __builtin_amdgcn_mfma_f32_16x16x32_bf16(ah, bl, acc[ct], 0, 0, 0);
            acc[ct] = __builtin_amdgcn_mfma_f32_16x16x32_bf16(al, bh, acc[ct], 0, 0, 0);
        }
    }
    // --- z-silu (waves 2,3): C/D layout col=fr-side, row=q*4+r ---
    if (wave >= 2) {
        #pragma unroll
        for (int ct = 0; ct < 4; ++ct) {
            int cz = (wave - 2) * 64 + ct * 16 + fr;   // z col in [0,128)
            float b2v = b_in[128 + cz];
            #pragma unroll
            for (int r = 0; r < 4; ++r) {
                float z = acc[ct][r] + b2v;
                float sig = 1.0f / (1.0f + __expf(-z));
                szs[q * 4 + r][cz] = z * sig;
            }
        }
    }
    __syncthreads();
    // --- u = rn * x1 * silu(z) (waves 0,1) ---
    if (wave < 2) {
        #pragma unroll
        for (int ct = 0; ct < 4; ++ct) {
            int cx = wave * 64 + ct * 16 + fr;
            float b1v = b_in[cx];
            #pragma unroll
            for (int r = 0; r < 4; ++r) {
                int row = q * 4 + r;
                float x1 = acc[ct][r] + b1v;
                us[row][cx] = rnS[row] * x1 * szs[row][cx];
            }
        }
    }
    __syncthreads();
    // --- pack & swizzled write-out (proven tail, unchanged) ---
    int j = t & 127, half = t >> 7;
    bf16x8 hv, lv;
    #pragma unroll
    for (int r = 0; r < 8; ++r) {
        float uv = us[half * 8 + r][j];
        unsigned short h = f2bf(uv);
        hv[r] = (short)h;
        lv[r] = (short)f2bf(uv - bf2f(h));
    }
    int b = row0 >> 10;
    int l0 = (row0 & 1023) + half * 8;
    size_t off = bswz(b, l0, j);
    *(bf16x8*)&uswH[off] = hv;
    *(bf16x8*)&uswL[off] = lv;
}

// ---------------------------------------------------------------------------
// R15 GEMM structure (frozen): 32x128 block tile, 8 waves = 4 n-slots x
// 2 k-split; per wave 8 ds_read_b128 -> 12 MFMAs; 3-buffer glds B ring at
// distance 2, single lgkm barrier per iter; kh-partials merged in epilogue.
// LDS = 119.7 KB, 1 block/CU (512 thr), 8 waves/CU.
// ---------------------------------------------------------------------------
#define STAGE_B(itS, nb)                                                        \
    _Pragma("unroll")                                                           \
    for (int j2 = 0; j2 < 4; ++j2) {                                            \
        int s = wave * 4 + j2;           /* [0,32) over 8 waves */              \
        int cts = s >> 4, s2 = s & 15;                                          \
        int qq = s2 & 3, nh = (s2 >> 2) & 1, hl = s2 >> 3;                      \
        size_t src0 = (size_t)((itS) * 2 + cts) * 4096;                         \
        const unsigned short* src =                                             \
            (hl ? BbL : BbH) + src0 + ((size_t)qq * 128 + nh * 64 + lane) * 8;  \
        unsigned short* dst =                                                   \
            (hl ? &sBl[nb][cts][0] : &sBh[nb][cts][0]) + qq * 1032 + nh * 512;  \
        __builtin_amdgcn_global_load_lds((gu32*)src, (lu32*)dst, 16, 0, 0);     \
    }

// k_g1 A write: one dword per chunk (c-pairs {2jj,2jj+1} and +32), 32 rows
#define G1_WRITE_A(nb, v0, v1, v2, v3)                                           \
    {                                                                            \
        unsigned short h0 = f2bf(v0), h1 = f2bf(v1);                             \
        unsigned short l0 = f2bf((v0) - bf2f(h0)), l1 = f2bf((v1) - bf2f(h1));   \
        *(unsigned int*)&sAh[nb][0][aoff] = (unsigned)h0 | ((unsigned)h1 << 16); \
        *(unsigned int*)&sAl[nb][0][aoff] = (unsigned)l0 | ((unsigned)l1 << 16); \
        unsigned short h2 = f2bf(v2), h3 = f2bf(v3);                             \
        unsigned short l2 = f2bf((v2) - bf2f(h2)), l3 = f2bf((v3) - bf2f(h3));   \
        *(unsigned int*)&sAh[nb][1][aoff] = (unsigned)h2 | ((unsigned)h3 << 16); \
        *(unsigned int*)&sAl[nb][1][aoff] = (unsigned)l2 | ((unsigned)l3 << 16); \
    }

// Per-wave: k-chunk kh only; 2 m-subtiles x 2 n-subtiles, acc[mt][nt].
#define MFMA_PHASE(aB, cB)                                                       \
    {                                                                            \
        __builtin_amdgcn_s_setprio(1);                                           \
        bf16x8 ah[2], al[2], bh[2], bl[2];                                       \
        _Pragma("unroll")                                                        \
        for (int mt = 0; mt < 2; ++mt) {                                         \
            int row = mt * 16 + fr;                                              \
            int p = (q + (row >> 3)) & 3;                                        \
            int offA = row * 40 + p * 8;                                         \
            ah[mt] = *(const bf16x8*)&sAh[aB][kh][offA];                         \
            al[mt] = *(const bf16x8*)&sAl[aB][kh][offA];                         \
        }                                                                        \
        _Pragma("unroll")                                                        \
        for (int nt = 0; nt < 2; ++nt) {                                         \
            int offB = q * 1032 + (wn + nt * 16 + fr) * 8;                       \
            bh[nt] = *(const bf16x8*)&sBh[cB][kh][offB];                         \
            bl[nt] = *(const bf16x8*)&sBl[cB][kh][offB];                         \
        }                                                                        \
        _Pragma("unroll")                                                        \
        for (int mt = 0; mt < 2; ++mt)                                           \
            _Pragma("unroll")                                                    \
            for (int nt = 0; nt < 2; ++nt) {                                     \
                acc[mt][nt] = __builtin_amdgcn_mfma_f32_16x16x32_bf16(ah[mt], bh[nt], acc[mt][nt], 0, 0, 0); \
                acc[mt][nt] = __builtin_amdgcn_mfma_f32_16x16x32_bf16(ah[mt], bl[nt], acc[mt][nt], 0, 0, 0); \
                acc[mt][nt] = __builtin_amdgcn_mfma_f32_16x16x32_bf16(al[mt], bh[nt], acc[mt][nt], 0, 0, 0); \
            }                                                                    \
        __builtin_amdgcn_s_setprio(0);                                           \
    }

// ---------------------------------------------------------------------------
// k_g1: GEMM1 (QTX = E^T @ u', tile 32k x 128d, BK=64) + gepi epilogue
// -> writes Gsw. Grid = 32 ktiles * 8 b = 256 blocks, 512 threads.
// R18 gepi: num = oma - den (exact identity) + pairwise common denominator
// (8 rcps instead of 16; pair product >= 1e-12, no underflow).
// ---------------------------------------------------------------------------
__global__ __launch_bounds__(512, 2) void k_g1(
    const float* __restrict__ E,
    const unsigned short* __restrict__ BH, const unsigned short* __restrict__ BL,
    const float* __restrict__ EigVals, const float* __restrict__ par,
    unsigned short* __restrict__ GswH, unsigned short* __restrict__ GswL) {
    __shared__ alignas(16) unsigned short sAh[2][2][1280], sAl[2][2][1280];
    __shared__ alignas(16) unsigned short sBh[3][2][4128], sBl[3][2][4128];
    __shared__ float evS[32];
    int bx = blockIdx.x;
    int b = bx & 7;
    int m0 = (bx >> 3) * 32;                 // k-tile base (32 tiles)
    const float* Ab = E + (size_t)b * (1024 * 1024);
    const unsigned short* BbH = BH + (size_t)b * 131072;
    const unsigned short* BbL = BL + (size_t)b * 131072;
    int t = threadIdx.x;
    int wave = t >> 6, lane = t & 63;
    int fr = lane & 15, q = lane >> 4;
    int kh = wave & 1;                        // k-split half
    int wn = (wave >> 1) * 32;                // n-slot
    // A staging: thread t handles m=am, c-pairs {2jj,2jj+1} (chunk0) and +32 (chunk1)
    int am = t & 31, jj = t >> 5;            // jj in [0,16)
    int ag = jj >> 2;
    int arot = (ag + (am >> 3)) & 3;
    int aoff = am * 40 + arot * 8 + ((2 * jj) & 7);
    if (t < 32) evS[t] = 1.0f - EigVals[b * 1024 + m0 + t];
    f32x4 acc[2][2];
    #pragma unroll
    for (int mt = 0; mt < 2; ++mt)
        #pragma unroll
        for (int nt = 0; nt < 2; ++nt)
            acc[mt][nt] = (f32x4){0.f, 0.f, 0.f, 0.f};

    // ---- prologue: B tiles 0,1 -> ring bufs 0,1; A tile 0 -> Abuf0 ----
    {
        STAGE_B(0, 0);
        STAGE_B(1, 1);
        float v0 = Ab[(size_t)(2 * jj) * 1024 + m0 + am];
        float v1 = Ab[(size_t)(2 * jj + 1) * 1024 + m0 + am];
        float v2 = Ab[(size_t)(32 + 2 * jj) * 1024 + m0 + am];
        float v3 = Ab[(size_t)(32 + 2 * jj + 1) * 1024 + m0 + am];
        G1_WRITE_A(0, v0, v1, v2, v3);
        asm volatile("s_waitcnt vmcnt(0) lgkmcnt(0)" ::: "memory");
        __builtin_amdgcn_s_barrier();
        asm volatile("" ::: "memory");
    }

    for (int it = 0; it < NIT_; ++it) {
        int cB = it % 3;
        int fB = (it + 2) % 3;
        int aB = it & 1, naB = aB ^ 1;
        float v0 = 0.f, v1 = 0.f, v2 = 0.f, v3 = 0.f;
        if (it + 1 < NIT_) {
            int cb = (it + 1) * 64;
            v0 = Ab[(size_t)(cb + 2 * jj) * 1024 + m0 + am];
            v1 = Ab[(size_t)(cb + 2 * jj + 1) * 1024 + m0 + am];
            v2 = Ab[(size_t)(cb + 32 + 2 * jj) * 1024 + m0 + am];
            v3 = Ab[(size_t)(cb + 32 + 2 * jj + 1) * 1024 + m0 + am];
        }
        if (it + 2 < NIT_) STAGE_B(it + 2, fB);
        // ---- compute on (aB, cB): 1 k-chunk (kh) x 12 MFMA per wave ----
        MFMA_PHASE(aB, cB)
        // ---- stage A(it+1); its compiler vmcnt-wait retires glds(it+1) too ----
        if (it + 1 < NIT_) G1_WRITE_A(naB, v0, v1, v2, v3);
        asm volatile("s_waitcnt lgkmcnt(0)" ::: "memory");
        __builtin_amdgcn_s_barrier();
        asm volatile("" ::: "memory");
    }

    // ---- epilogue phase 1: kh-merge partial accs into Gs (aliased onto sBh) ----
    float (*Gs)[132] = (float (*)[132])(&sBh[0][0][0]);
    if (kh == 0) {
        #pragma unroll
        for (int mt = 0; mt < 2; ++mt)
            #pragma unroll
            for (int nt = 0; nt < 2; ++nt) {
                int col = wn + nt * 16 + fr;
                #pragma unroll
                for (int r = 0; r < 4; ++r)
                    Gs[mt * 16 + q * 4 + r][col] = acc[mt][nt][r];
            }
    }
    __syncthreads();
    if (kh == 1) {
        #pragma unroll
        for (int mt = 0; mt < 2; ++mt)
            #pragma unroll
            for (int nt = 0; nt < 2; ++nt) {
                int col = wn + nt * 16 + fr;
                #pragma unroll
                for (int r = 0; r < 4; ++r)
                    Gs[mt * 16 + q * 4 + r][col] += acc[mt][nt][r];
            }
    }
    __syncthreads();
    // ---- phase 2: Gs *= w(ev,col); pairwise-denominator rational sum ----
    {
        int col = t & 127, rowg = t >> 7;    // 4 groups x 8 rows
        float arr[S_], aii[S_], ccc[S_];
        #pragma unroll
        for (int ss = 0; ss < S_; ++ss) {
            arr[ss] = par[ss * D_ + col];
            aii[ss] = par[DS_ + ss * D_ + col];
            ccc[ss] = par[2 * DS_ + ss * D_ + col];
        }
        #pragma unroll
        for (int i = 0; i < 8; ++i) {
            int row = rowg * 8 + i;
            float ev = evS[row];
            float w = 0.f;
            #pragma unroll
            for (int sp = 0; sp < 8; ++sp) {
                float n0, n1, d0, d1;
                {
                    int ss = sp * 2;
                    float a = ev * arr[ss], bi = ev * aii[ss];
                    float oma = 1.0f - a;            // exact (Sterbenz)
                    d0 = fmaf(oma, oma, bi * bi);    // den, no cancellation
                    n0 = ccc[ss] * (oma - d0);       // num = a*oma - b^2 == oma - den
                }
                {
                    int ss = sp * 2 + 1;
                    float a = ev * arr[ss], bi = ev * aii[ss];
                    float oma = 1.0f - a;
                    d1 = fmaf(oma, oma, bi * bi);
                    n1 = ccc[ss] * (oma - d1);
                }
                float num = fmaf(n0, d1, n1 * d0);
                float dpr = d0 * d1;                 // >= ~1e-12, no underflow
                float rr = __builtin_amdgcn_rcpf(dpr);
                rr = rr * (2.0f - dpr * rr);
                w = fmaf(num, rr, w);
            }
            Gs[row][col] *= w;
        }
    }
    __syncthreads();
    // ---- phase 3: swizzled bf16 hi/lo write-out (32 rows = one full ct) ----
    {
        int d = t & 127, kg = t >> 7;        // kg in [0,4): rows kg*8..+8
        bf16x8 hv, lv;
        #pragma unroll
        for (int i = 0; i < 8; ++i) {
            float v = Gs[kg * 8 + i][d];
            unsigned short h = f2bf(v);
            hv[i] = (short)h;
            lv[i] = (short)f2bf(v - bf2f(h));
        }
        int ct = m0 >> 5;
        size_t off = (((size_t)(b * 32 + ct) * 4 + kg) * 128 + d) * 8;
        *(bf16x8*)&GswH[off] = hv;
        *(bf16x8*)&GswL[off] = lv;
    }
}

// ---------------------------------------------------------------------------
// k_g2 (frozen R17): GEMM2 + rn/silu + MFMA out-proj epilogue -> writes y.
// ---------------------------------------------------------------------------
#define G2_WRITE_A(nb, va)                                                       \
    {                                                                            \
        unsigned short h0 = f2bf((va).x), h1 = f2bf((va).y);                     \
        unsigned short h2 = f2bf((va).z), h3 = f2bf((va).w);                     \
        unsigned short l0 = f2bf((va).x - bf2f(h0)), l1 = f2bf((va).y - bf2f(h1));\
        unsigned short l2 = f2bf((va).z - bf2f(h2)), l3 = f2bf((va).w - bf2f(h3));\
        *(uint2*)&sAh[nb][chunk][aoff] =                                         \
            (uint2){(unsigned)h0 | ((unsigned)h1 << 16),                         \
                    (unsigned)h2 | ((unsigned)h3 << 16)};                        \
        *(uint2*)&sAl[nb][chunk][aoff] =                                         \
            (uint2){(unsigned)l0 | ((unsigned)l1 << 16),                         \
                    (unsigned)l2 | ((unsigned)l3 << 16)};                        \
    }

__global__ __launch_bounds__(512, 2) void k_g2(
    const float* __restrict__ E,
    const unsigned short* __restrict__ BH, const unsigned short* __restrict__ BL,
    const float* __restrict__ rn,
    const unsigned short* __restrict__ woH, const unsigned short* __restrict__ woL,
    const float* __restrict__ b_out, float* __restrict__ y) {
    __shared__ alignas(16) unsigned short sAh[2][2][1280], sAl[2][2][1280];
    __shared__ alignas(16) unsigned short sBh[3][2][4128], sBl[3][2][4128];
    __shared__ float rnS[32];
    int bx = blockIdx.x;
    int b = bx & 7;
    int m0 = (bx >> 3) * 32;                 // l-tile base
    const float* Ab = E + (size_t)b * (1024 * 1024);
    const unsigned short* BbH = BH + (size_t)b * 131072;
    const unsigned short* BbL = BL + (size_t)b * 131072;
    int t = threadIdx.x;
    int wave = t >> 6, lane = t & 63;
    int fr = lane & 15, q = lane >> 4;
    int kh = wave & 1;
    int wn = (wave >> 1) * 32;
    // A staging: thread t loads E[m0+am][cb + c4 .. +4] (float4, row-major)
    int am = t >> 4, c4 = (t & 15) * 4;      // am in [0,32), c4 in [0,64)
    int chunk = c4 >> 5, cw = c4 & 31;
    int ag = cw >> 3;
    int arot = (ag + (am >> 3)) & 3;
    int aoff = am * 40 + arot * 8 + (cw & 7);
    if (t < 32) rnS[t] = rn[b * 1024 + m0 + t];
    f32x4 acc[2][2];
    #pragma unroll
    for (int mt = 0; mt < 2; ++mt)
        #pragma unroll
        for (int nt = 0; nt < 2; ++nt)
            acc[mt][nt] = (f32x4){0.f, 0.f, 0.f, 0.f};

    // ---- prologue ----
    {
        STAGE_B(0, 0);
        STAGE_B(1, 1);
        float4 va = *(const float4*)&Ab[(size_t)(m0 + am) * 1024 + c4];
        G2_WRITE_A(0, va);
        asm volatile("s_waitcnt vmcnt(0) lgkmcnt(0)" ::: "memory");
        __builtin_amdgcn_s_barrier();
        asm volatile("" ::: "memory");
    }

    for (int it = 0; it < NIT_; ++it) {
        int cB = it % 3;
        int fB = (it + 2) % 3;
        int aB = it & 1, naB = aB ^ 1;
        float4 va = (float4){0.f, 0.f, 0.f, 0.f};
        if (it + 1 < NIT_)
            va = *(const float4*)&Ab[(size_t)(m0 + am) * 1024 + (it + 1) * 64 + c4];
        if (it + 2 < NIT_) STAGE_B(it + 2, fB);
        MFMA_PHASE(aB, cB)
        if (it + 1 < NIT_) G2_WRITE_A(naB, va);
        asm volatile("s_waitcnt lgkmcnt(0)" ::: "memory");
        __builtin_amdgcn_s_barrier();
        asm volatile("" ::: "memory");
    }

    // ---- epilogue: kh-merge raw accs into Ysf (aliased onto sBh) ----
    float (*Ysf)[132] = (float (*)[132])(&sBh[0][0][0]);
    if (kh == 0) {
        #pragma unroll
        for (int mt = 0; mt < 2; ++mt)
            #pragma unroll
            for (int nt = 0; nt < 2; ++nt) {
                int col = wn + nt * 16 + fr;
                #pragma unroll
                for (int r = 0; r < 4; ++r)
                    Ysf[mt * 16 + q * 4 + r][col] = acc[mt][nt][r];
            }
    }
    __syncthreads();
    if (kh == 1) {
        #pragma unroll
        for (int mt = 0; mt < 2; ++mt)
            #pragma unroll
            for (int nt = 0; nt < 2; ++nt) {
                int col = wn + nt * 16 + fr;
                #pragma unroll
                for (int r = 0; r < 4; ++r)
                    Ysf[mt * 16 + q * 4 + r][col] += acc[mt][nt][r];
            }
    }
    __syncthreads();
    // ---- rn + silu -> bf16 hi/lo A-tile in dead sBl (padded 40-short rows) ----
    unsigned short (*ysh)[32][40] = (unsigned short (*)[32][40])(&sBl[0][0][0]);
    unsigned short (*ysl)[32][40] = (unsigned short (*)[32][40])(&sBl[0][0][0] + 5120);
    {
        int col = t & 127, rowg = t >> 7;    // 4 groups x 8 rows
        #pragma unroll
        for (int i = 0; i < 8; ++i) {
            int row = rowg * 8 + i;
            float v = Ysf[row][col] * rnS[row];
            float sig = 1.0f / (1.0f + __expf(-v));
            float u = v * sig;
            unsigned short h = f2bf(u);
            ysh[col >> 5][row][col & 31] = h;
            ysl[col >> 5][row][col & 31] = f2bf(u - bf2f(h));
        }
    }
    __syncthreads();
    // ---- MFMA out-proj: wave (mh = wave&1 m-half, ws = wave>>1 n-slot) ----
    {
        int mh = wave & 1, ws = wave >> 1;
        const bf16x8* WH = (const bf16x8*)woH;
        const bf16x8* WL = (const bf16x8*)woL;
        f32x4 a2[2];
        a2[0] = (f32x4){0.f, 0.f, 0.f, 0.f};
        a2[1] = (f32x4){0.f, 0.f, 0.f, 0.f};
        #pragma unroll
        for (int kc = 0; kc < 4; ++kc) {
            bf16x8 ah = *(const bf16x8*)&ysh[kc][mh * 16 + fr][q * 8];
            bf16x8 al = *(const bf16x8*)&ysl[kc][mh * 16 + fr][q * 8];
            #pragma unroll
            for (int nt = 0; nt < 2; ++nt) {
                bf16x8 bh = WH[((kc * 4 + ws) * 2 + nt) * 64 + lane];
                bf16x8 bl = WL[((kc * 4 + ws) * 2 + nt) * 64 + lane];
                a2[nt] = __builtin_amdgcn_mfma_f32_16x16x32_bf16(ah, bh, a2[nt], 0, 0, 0);
                a2[nt] = __builtin_amdgcn_mfma_f32_16x16x32_bf16(ah, bl, a2[nt], 0, 0, 0);
                a2[nt] = __builtin_amdgcn_mfma_f32_16x16x32_bf16(al, bh, a2[nt], 0, 0, 0);
            }
        }
        #pragma unroll
        for (int nt = 0; nt < 2; ++nt) {
            int col = ws * 32 + nt * 16 + fr;
            float bo = b_out[col];
            #pragma unroll
            for (int r = 0; r < 4; ++r) {
                int row = mh * 16 + q * 4 + r;
                y[((size_t)b * 1024 + m0 + row) * 128 + col] = a2[nt][r] + bo;
            }
        }
    }
}

// ---------------------------------------------------------------------------
extern "C" void kernel_launch(void* const* d_in, const int* in_sizes, int n_in,
                              void* d_out, int out_size, void* d_ws, size_t ws_size,
                              hipStream_t stream) {
    const float* x          = (const float*)d_in[0];
    const float* EigVecs    = (const float*)d_in[2];
    const float* EigVals    = (const float*)d_in[3];
    const float* bn_gamma   = (const float*)d_in[4];
    const float* bn_beta    = (const float*)d_in[5];
    const float* bn_mean    = (const float*)d_in[6];
    const float* bn_var     = (const float*)d_in[7];
    const float* W_in       = (const float*)d_in[8];
    const float* b_in       = (const float*)d_in[9];
    const float* log_Delta  = (const float*)d_in[10];
    const float* Bp         = (const float*)d_in[11];
    const float* Cp         = (const float*)d_in[12];
    const float* log_A_real = (const float*)d_in[13];
    const float* A_imag     = (const float*)d_in[14];
    const float* W_out      = (const float*)d_in[15];
    const float* b_out      = (const float*)d_in[16];

    float* y = (float*)d_out;
    char* w = (char*)d_ws;
    float* rn            = (float*)(w);                       // 32 KB
    float* par           = (float*)(w + 32768);               // 24 KB
    unsigned short* woH  = (unsigned short*)(w + 57344);      // 32 KB
    unsigned short* woL  = (unsigned short*)(w + 90112);      // 32 KB
    unsigned short* wiH  = (unsigned short*)(w + 131072);     // 64 KB
    unsigned short* wiL  = (unsigned short*)(w + 196608);     // 64 KB
    unsigned short* uswH = (unsigned short*)(w + 262144);     // 2 MB each
    unsigned short* uswL = (unsigned short*)(w + 262144 + (1u << 21));
    unsigned short* GswH = (unsigned short*)(w + 262144 + 2 * (1u << 21));
    unsigned short* GswL = (unsigned short*)(w + 262144 + 3 * (1u << 21));

    k_w<<<dim3(16), dim3(256), 0, stream>>>(W_in, wiH, wiL);
    k_pre<<<dim3(B_ * L_ / 16), dim3(256), 0, stream>>>(
        EigVecs, x, bn_gamma, bn_beta, bn_mean, bn_var, wiH, wiL, b_in,
        log_Delta, Bp, Cp, log_A_real, A_imag, W_out, rn, par, woH, woL,
        uswH, uswL);
    k_g1<<<dim3(256), dim3(512), 0, stream>>>(
        EigVecs, uswH, uswL, EigVals, par, GswH, GswL);
    k_g2<<<dim3(256), dim3(512), 0, stream>>>(
        EigVecs, GswH, GswL, rn, woH, woL, b_out, y);
}